// Round 3
// baseline (989.195 us; speedup 1.0000x reference)
//
#include <hip/hip_runtime.h>
#include <math.h>
#include <cfloat>
#include <climits>

#define NROW 4096
#define DIM  2048
#define BIGF 100000.0f

typedef float  f32x4  __attribute__((ext_vector_type(4)));
typedef __bf16 bf16x8 __attribute__((ext_vector_type(8)));
typedef unsigned short us8v __attribute__((ext_vector_type(8)));

// ---------------------------------------------------------------------------
// bf16 helpers (RNE, no NaN handling needed here)
// ---------------------------------------------------------------------------
__device__ __forceinline__ unsigned short f2bf(float x) {
    unsigned u = __float_as_uint(x);
    u += 0x7fffu + ((u >> 16) & 1u);
    return (unsigned short)(u >> 16);
}
__device__ __forceinline__ float bf2f(unsigned short h) {
    return __uint_as_float(((unsigned)h) << 16);
}

// async global->LDS, 16B per lane (dest must be linear: wave-uniform base + lane*16)
__device__ __forceinline__ void gload16(const void* g, void* lds) {
    __builtin_amdgcn_global_load_lds(
        (const __attribute__((address_space(1))) unsigned int*)g,
        (__attribute__((address_space(3))) unsigned int*)lds,
        16, 0, 0);
}

// ---------------------------------------------------------------------------
// Kernel 1: row L2-normalize + 2-term bf16 split (hi=bf16(x), lo=bf16(x-hi))
// + squared-norm-after-normalize. Reference divides by max(norm,1e-12).
// ---------------------------------------------------------------------------
__global__ __launch_bounds__(256) void k_norm_split(const float* __restrict__ in,
    unsigned short* __restrict__ hi, unsigned short* __restrict__ lo,
    float* __restrict__ sq)
{
    int row = blockIdx.x;
    int tid = threadIdx.x;
    const float4* rp = (const float4*)(in + (size_t)row * DIM);
    float4 v0 = rp[tid * 2 + 0];
    float4 v1 = rp[tid * 2 + 1];
    float ss = v0.x*v0.x + v0.y*v0.y + v0.z*v0.z + v0.w*v0.w
             + v1.x*v1.x + v1.y*v1.y + v1.z*v1.z + v1.w*v1.w;
    #pragma unroll
    for (int off = 32; off > 0; off >>= 1) ss += __shfl_down(ss, off, 64);
    __shared__ float wsum[4];
    __shared__ float s_den;
    if ((tid & 63) == 0) wsum[tid >> 6] = ss;
    __syncthreads();
    if (tid == 0) {
        float tot = wsum[0] + wsum[1] + wsum[2] + wsum[3];
        float den = fmaxf(sqrtf(tot), 1e-12f);
        s_den = den;
        sq[row] = tot / (den * den);
    }
    __syncthreads();
    float den = s_den;
    float xs[8];
    xs[0]=v0.x/den; xs[1]=v0.y/den; xs[2]=v0.z/den; xs[3]=v0.w/den;
    xs[4]=v1.x/den; xs[5]=v1.y/den; xs[6]=v1.z/den; xs[7]=v1.w/den;
    us8v hv, lv;
    #pragma unroll
    for (int j = 0; j < 8; ++j) {
        unsigned short h = f2bf(xs[j]);
        hv[j] = h;
        lv[j] = f2bf(xs[j] - bf2f(h));
    }
    *(us8v*)&hi[(size_t)row * DIM + tid * 8] = hv;
    *(us8v*)&lo[(size_t)row * DIM + tid * 8] = lv;
}

// ---------------------------------------------------------------------------
// Kernel 2: dual MFMA GEMM over split-bf16 operands, fused pdist epilogue.
//   TT ~= T1*T1' + T1*T2' + T2*T1';  TS ~= T1*S1' + T1*S2' + T2*S1'
// (missing hi-residual x residual term ~2^-18 rel, below fp32 reorder noise)
// Structure = m97 ladder: 128x128 tile, BK=32, 4 waves (2x2), each wave 64x64
// = 4x4 frags of 16x16x32 bf16 MFMA, global_load_lds width 16, 2 barriers/step.
// LDS tiles are [128 rows][32 k] bf16, 16B-chunk XOR-swizzled by (row&3)
// (both-sides swizzle: pre-swizzled GLOBAL source + swizzled ds_read).
// ---------------------------------------------------------------------------
__global__ __launch_bounds__(256, 2) void k_gemm_mfma(
    const unsigned short* __restrict__ T1, const unsigned short* __restrict__ T2,
    const unsigned short* __restrict__ S1, const unsigned short* __restrict__ S2,
    const float* __restrict__ t2v, const float* __restrict__ s2v,
    float* __restrict__ distT, float* __restrict__ distS)
{
    __shared__ unsigned short As[128 * 32];   // 8 KB
    __shared__ unsigned short Bt[128 * 32];
    __shared__ unsigned short Bs[128 * 32];

    int tid = threadIdx.x;

    // bijective XCD-aware swizzle (nwg = 1024, 1024 % 8 == 0)
    int orig  = blockIdx.y * gridDim.x + blockIdx.x;
    int nwg   = gridDim.x * gridDim.y;
    int cpx   = nwg >> 3;
    int swz   = (orig & 7) * cpx + (orig >> 3);
    int bx    = swz % gridDim.x;
    int by    = swz / gridDim.x;
    int m0 = by * 128, n0 = bx * 128;

    // staging decomposition: thread t covers row r0 = t/4, 16B chunk t%3... t&3
    int r0   = tid >> 2;                       // 0..63
    int cs0  = ((tid & 3) ^ (r0 & 3)) << 4;    // swizzled source chunk, bytes
    unsigned ldst = (unsigned)tid * 16;        // linear LDS dest within issue

    // wave/fragment geometry
    int l  = tid & 63;
    int w  = tid >> 6;
    int wr = w >> 1, wc = w & 1;               // wave tile (2x2 of 64x64)
    int lr = l & 15;                           // fragment lane row/col
    int kc = l >> 4;                           // k-chunk 0..3 (8 bf16 each)

    f32x4 acc_t[4][4], acc_s[4][4];
    #pragma unroll
    for (int m = 0; m < 4; ++m)
        #pragma unroll
        for (int n = 0; n < 4; ++n) {
            acc_t[m][n] = (f32x4)0.0f;
            acc_s[m][n] = (f32x4)0.0f;
        }

    const unsigned short* segA[3]  = {T1, T1, T2};
    const unsigned short* segBt[3] = {T1, T2, T1};
    const unsigned short* segBs[3] = {S1, S2, S1};

    for (int seg = 0; seg < 3; ++seg) {
        const char* pA  = (const char*)segA[seg];
        const char* pBt = (const char*)segBt[seg];
        const char* pBs = (const char*)segBs[seg];
        for (int k0 = 0; k0 < DIM; k0 += 32) {
            size_t gA0 = ((size_t)(m0 + r0)      * DIM + k0) * 2 + cs0;
            size_t gA1 = ((size_t)(m0 + 64 + r0) * DIM + k0) * 2 + cs0;
            size_t gB0 = ((size_t)(n0 + r0)      * DIM + k0) * 2 + cs0;
            size_t gB1 = ((size_t)(n0 + 64 + r0) * DIM + k0) * 2 + cs0;
            gload16(pA  + gA0, (char*)As + ldst);
            gload16(pA  + gA1, (char*)As + 4096 + ldst);
            gload16(pBt + gB0, (char*)Bt + ldst);
            gload16(pBt + gB1, (char*)Bt + 4096 + ldst);
            gload16(pBs + gB0, (char*)Bs + ldst);
            gload16(pBs + gB1, (char*)Bs + 4096 + ldst);
            __syncthreads();   // drains vmcnt before barrier (compiler-enforced)

            bf16x8 a[4], btf[4], bsf[4];
            #pragma unroll
            for (int m = 0; m < 4; ++m) {
                int ra = wr * 64 + m * 16 + lr;
                a[m] = *(const bf16x8*)((const char*)As + ra * 64 + ((kc ^ (ra & 3)) << 4));
            }
            #pragma unroll
            for (int n = 0; n < 4; ++n) {
                int rb = wc * 64 + n * 16 + lr;
                int co = (kc ^ (rb & 3)) << 4;
                btf[n] = *(const bf16x8*)((const char*)Bt + rb * 64 + co);
                bsf[n] = *(const bf16x8*)((const char*)Bs + rb * 64 + co);
            }
            #pragma unroll
            for (int m = 0; m < 4; ++m)
                #pragma unroll
                for (int n = 0; n < 4; ++n) {
                    acc_t[m][n] = __builtin_amdgcn_mfma_f32_16x16x32_bf16(
                        a[m], btf[n], acc_t[m][n], 0, 0, 0);
                    acc_s[m][n] = __builtin_amdgcn_mfma_f32_16x16x32_bf16(
                        a[m], bsf[n], acc_s[m][n], 0, 0, 0);
                }
            __syncthreads();
        }
    }

    // epilogue: dist = sqrt(max(a2_row + b2_col - 2*dot, 1e-12))
    // C/D layout (m89-verified): col = lane&15, row = (lane>>4)*4 + reg
    int colb = n0 + wc * 64 + lr;
    int rowb = m0 + wr * 64 + (kc << 2);
    float t2row[4][4];
    #pragma unroll
    for (int m = 0; m < 4; ++m)
        #pragma unroll
        for (int r = 0; r < 4; ++r) t2row[m][r] = t2v[rowb + m * 16 + r];
    #pragma unroll
    for (int n = 0; n < 4; ++n) {
        int col = colb + n * 16;
        float t2c = t2v[col];
        float s2c = s2v[col];
        #pragma unroll
        for (int m = 0; m < 4; ++m) {
            f32x4 ct = acc_t[m][n];
            f32x4 cs = acc_s[m][n];
            int row = rowb + m * 16;
            #pragma unroll
            for (int r = 0; r < 4; ++r) {
                size_t o = (size_t)(row + r) * NROW + col;
                distT[o] = sqrtf(fmaxf(t2row[m][r] + t2c - 2.0f * ct[r], 1e-12f));
                distS[o] = sqrtf(fmaxf(t2row[m][r] + s2c - 2.0f * cs[r], 1e-12f));
            }
        }
    }
}

// ---------------------------------------------------------------------------
// Kernel 3: per-row mining. One block (256 thr) per row i.  (unchanged)
// ---------------------------------------------------------------------------
__device__ inline float pair_term(float an_v, float ap_v, float an_t, float ap_t)
{
    float w_an = fmaxf(an_t - an_v, 0.f);
    float w_ap = fmaxf(ap_v - ap_t, 0.f);
    float l0 = w_an * an_v / 0.04f;
    float l1 = w_ap * ap_v / 0.04f;
    float mx = fmaxf(l0, l1);
    return mx + logf(expf(l0 - mx) + expf(l1 - mx)) - l0;
}

__device__ void argred_min(float* rv, int* ri, int tid, float &ov, int &oi)
{
    __syncthreads();
    for (int s = 128; s > 0; s >>= 1) {
        if (tid < s) {
            float v2 = rv[tid+s]; int i2 = ri[tid+s];
            if (v2 < rv[tid] || (v2 == rv[tid] && i2 < ri[tid])) { rv[tid] = v2; ri[tid] = i2; }
        }
        __syncthreads();
    }
    ov = rv[0]; oi = ri[0];
    __syncthreads();
}

__device__ void argred_max(float* rv, int* ri, int tid, float &ov, int &oi)
{
    __syncthreads();
    for (int s = 128; s > 0; s >>= 1) {
        if (tid < s) {
            float v2 = rv[tid+s]; int i2 = ri[tid+s];
            if (v2 > rv[tid] || (v2 == rv[tid] && i2 < ri[tid])) { rv[tid] = v2; ri[tid] = i2; }
        }
        __syncthreads();
    }
    ov = rv[0]; oi = ri[0];
    __syncthreads();
}

// radix-select the (rank)-th smallest (0-based) masked value; positive floats
// compare as their uint bits. Masked-out key = 0xFFFFFFFF (never selected
// since rank < count). Returns value and FIRST matching index.
__device__ void radix_select(const float* d_row, const float* dt_row, float temp1,
                             bool selNeg, int rank, unsigned* hist, unsigned* s_sel,
                             int* ri, int tid, float &val, int &idx)
{
    unsigned prefix = 0;
    int r = rank;
    for (int shift = 24; shift >= 0; shift -= 8) {
        hist[tid] = 0;
        __syncthreads();
        for (int j = tid; j < NROW; j += 256) {
            bool neg = dt_row[j] > temp1;
            unsigned key = (neg == selNeg) ? __float_as_uint(d_row[j]) : 0xFFFFFFFFu;
            bool match = (shift == 24) || ((key >> (shift + 8)) == (prefix >> (shift + 8)));
            if (match) atomicAdd(&hist[(key >> shift) & 255u], 1u);
        }
        __syncthreads();
        if (tid == 0) {
            unsigned c = 0; unsigned b = 0;
            for (; b < 256; ++b) {
                unsigned h = hist[b];
                if (c + h > (unsigned)r) break;
                c += h;
            }
            if (b > 255) b = 255;
            s_sel[0] = b;
            s_sel[1] = (unsigned)(r - (int)c);
        }
        __syncthreads();
        prefix |= s_sel[0] << shift;
        r = (int)s_sel[1];
        __syncthreads();
    }
    int best = INT_MAX;
    for (int j = tid; j < NROW; j += 256) {
        bool neg = dt_row[j] > temp1;
        unsigned key = (neg == selNeg) ? __float_as_uint(d_row[j]) : 0xFFFFFFFFu;
        if (key == prefix && j < best) best = j;
    }
    ri[tid] = best;
    __syncthreads();
    for (int s = 128; s > 0; s >>= 1) {
        if (tid < s) { if (ri[tid+s] < ri[tid]) ri[tid] = ri[tid+s]; }
        __syncthreads();
    }
    val = __uint_as_float(prefix);
    idx = ri[0];
    __syncthreads();
}

__global__ __launch_bounds__(256) void k_rowstats(const float* __restrict__ distS,
    const float* __restrict__ distT, float* __restrict__ terms)
{
    __shared__ float d_row[NROW];
    __shared__ float dt_row[NROW];
    __shared__ float rv[256];
    __shared__ int ri[256];
    __shared__ unsigned hist[256];
    __shared__ unsigned s_sel[2];
    __shared__ int s_cnt;

    int i = blockIdx.x, tid = threadIdx.x;
    const float4* dp  = (const float4*)(distS + (size_t)i * NROW);
    const float4* dtp = (const float4*)(distT + (size_t)i * NROW);
    float4* d4  = (float4*)d_row;
    float4* dt4 = (float4*)dt_row;
    for (int j = tid; j < NROW/4; j += 256) { d4[j] = dp[j]; dt4[j] = dtp[j]; }
    if (tid == 0) s_cnt = 0;
    __syncthreads();

    float temp1 = d_row[i];   // dist[i,i]

    float v_an = FLT_MAX;  int i_an = INT_MAX;   // min over (neg? d : BIG)
    float v_ap = -FLT_MAX; int i_ap = INT_MAX;   // max over (pos? d : 0)
    float v_ane = -FLT_MAX; int i_ane = INT_MAX; // max over (neg? d : 0)
    float v_ape = FLT_MAX;  int i_ape = INT_MAX; // min over (pos? d : BIG)
    int cnt = 0;
    for (int j = tid; j < NROW; j += 256) {
        float d = d_row[j];
        bool neg = dt_row[j] > temp1;
        cnt += neg ? 1 : 0;
        float c_an  = neg ? d : BIGF;
        float c_ap  = neg ? 0.f : d;
        float c_ane = neg ? d : 0.f;
        float c_ape = neg ? BIGF : d;
        if (c_an  < v_an)  { v_an  = c_an;  i_an  = j; }
        if (c_ap  > v_ap)  { v_ap  = c_ap;  i_ap  = j; }
        if (c_ane > v_ane) { v_ane = c_ane; i_ane = j; }
        if (c_ape < v_ape) { v_ape = c_ape; i_ape = j; }
    }
    atomicAdd(&s_cnt, cnt);

    float an_v, ap_v, ane_v, ape_v;
    int an_i, ap_i, ane_i, ape_i;
    rv[tid] = v_an;  ri[tid] = i_an;  argred_min(rv, ri, tid, an_v,  an_i);
    rv[tid] = v_ap;  ri[tid] = i_ap;  argred_max(rv, ri, tid, ap_v,  ap_i);
    rv[tid] = v_ane; ri[tid] = i_ane; argred_max(rv, ri, tid, ane_v, ane_i);
    rv[tid] = v_ape; ri[tid] = i_ape; argred_min(rv, ri, tid, ape_v, ape_i);

    int k_neg = s_cnt;
    int k_pos = NROW - k_neg;

    float mn_v; int mn_i;
    if (k_neg > 0) {
        radix_select(d_row, dt_row, temp1, true, (k_neg - 1) >> 1, hist, s_sel, ri, tid, mn_v, mn_i);
    } else {
        mn_v = 0.f; mn_i = 0;
        __syncthreads();
    }
    float mp_v; int mp_i;
    radix_select(d_row, dt_row, temp1, false, (k_pos - 1) >> 1, hist, s_sel, ri, tid, mp_v, mp_i);

    if (tid == 0) {
        float an_t  = dt_row[an_i];
        float ap_t  = dt_row[ap_i];
        float ane_t = dt_row[ane_i];
        float ape_t = dt_row[ape_i];
        float mn_t  = dt_row[mn_i];
        float mp_t  = dt_row[mp_i];
        terms[i]            = pair_term(an_v,  ap_v,  an_t,  ap_t);   // d-branch
        terms[NROW + i]     = pair_term(ane_v, ape_v, ane_t, ape_t);  // e-branch
        terms[2*NROW + i]   = pair_term(mn_v,  mp_v,  mn_t,  mp_t);   // m-branch
    }
}

// ---------------------------------------------------------------------------
// Kernel 4: deterministic final reduction + decay weights from epoch.
// ---------------------------------------------------------------------------
__global__ __launch_bounds__(256) void k_finalize(const float* __restrict__ terms,
    const void* __restrict__ epoch_p, float* __restrict__ out)
{
    __shared__ float red[256];
    int tid = threadIdx.x;
    float s0 = 0.f, s1 = 0.f, s2 = 0.f;
    for (int j = tid; j < NROW; j += 256) {
        s0 += terms[j];
        s1 += terms[NROW + j];
        s2 += terms[2*NROW + j];
    }
    float tot[3];
    float sv[3] = {s0, s1, s2};
    for (int t = 0; t < 3; ++t) {
        red[tid] = sv[t];
        __syncthreads();
        for (int st = 128; st > 0; st >>= 1) {
            if (tid < st) red[tid] += red[tid + st];
            __syncthreads();
        }
        tot[t] = red[0];
        __syncthreads();
    }
    if (tid == 0) {
        int ei = *(const int*)epoch_p;
        double step;
        if (ei >= 0 && ei < 100000) step = (double)ei;          // passed as int
        else step = (double)(*(const float*)epoch_p);           // passed as float
        const double PI = 3.14159265358979323846;
        double de = 0.5 * 0.75 * (1.0 + cos(PI * step / 120.0));
        double dm = 0.5 * 0.75 * (1.0 + cos(PI * step / 240.0));
        double e = (step < 120.0) ? de : 0.0;
        double m = dm;
        double d = 3.0 - e - m;
        double loss_d = (double)tot[0] / (double)NROW;
        double loss_e = (double)tot[1] / (double)NROW;
        double loss_m = (double)tot[2] / (double)NROW;
        out[0] = (float)(loss_e * e + loss_m * m + loss_d * d);
    }
}

// ---------------------------------------------------------------------------
extern "C" void kernel_launch(void* const* d_in, const int* in_sizes, int n_in,
                              void* d_out, int out_size, void* d_ws, size_t ws_size,
                              hipStream_t stream)
{
    (void)in_sizes; (void)n_in; (void)out_size; (void)ws_size;
    const float* t_in = (const float*)d_in[0];
    const float* s_in = (const float*)d_in[1];
    const void*  epoch = d_in[2];
    float* out = (float*)d_out;

    char* ws = (char*)d_ws;
    size_t off = 0;
    unsigned short* T1 = (unsigned short*)(ws + off); off += (size_t)NROW * DIM * 2; // 16.8 MB
    unsigned short* T2 = (unsigned short*)(ws + off); off += (size_t)NROW * DIM * 2;
    unsigned short* S1 = (unsigned short*)(ws + off); off += (size_t)NROW * DIM * 2;
    unsigned short* S2 = (unsigned short*)(ws + off); off += (size_t)NROW * DIM * 2;
    float* t2v   = (float*)(ws + off); off += (size_t)NROW * 4;
    float* s2v   = (float*)(ws + off); off += (size_t)NROW * 4;
    float* distT = (float*)(ws + off); off += (size_t)NROW * NROW * 4;  // 67.1 MB
    float* distS = (float*)(ws + off); off += (size_t)NROW * NROW * 4;  // 67.1 MB
    float* terms = (float*)(ws + off); off += (size_t)3 * NROW * 4;
    // total ~201.4 MB of workspace

    k_norm_split<<<NROW, 256, 0, stream>>>(t_in, T1, T2, t2v);
    k_norm_split<<<NROW, 256, 0, stream>>>(s_in, S1, S2, s2v);
    k_gemm_mfma<<<dim3(32, 32), 256, 0, stream>>>(T1, T2, S1, S2, t2v, s2v, distT, distS);
    k_rowstats<<<NROW, 256, 0, stream>>>(distS, distT, terms);
    k_finalize<<<1, 256, 0, stream>>>(terms, epoch, out);
}

// Round 5
// 679.072 us; speedup vs baseline: 1.4567x; 1.4567x over previous
//
#include <hip/hip_runtime.h>
#include <math.h>
#include <cfloat>
#include <climits>

#define NROW 4096
#define DIM  2048
#define BIGF 100000.0f
#define BIGU 0x47C35000u   // bits of 100000.0f

typedef float  f32x4  __attribute__((ext_vector_type(4)));
typedef __bf16 bf16x8 __attribute__((ext_vector_type(8)));
typedef unsigned short us8v __attribute__((ext_vector_type(8)));

// ---------------------------------------------------------------------------
// bf16 helpers (RNE)
// ---------------------------------------------------------------------------
__device__ __forceinline__ unsigned short f2bf(float x) {
    unsigned u = __float_as_uint(x);
    u += 0x7fffu + ((u >> 16) & 1u);
    return (unsigned short)(u >> 16);
}
__device__ __forceinline__ float bf2f(unsigned short h) {
    return __uint_as_float(((unsigned)h) << 16);
}

// async global->LDS, 16B per lane (dest linear: wave-uniform base + lane*16)
__device__ __forceinline__ void gload16(const void* g, void* lds) {
    __builtin_amdgcn_global_load_lds(
        (const __attribute__((address_space(1))) unsigned int*)g,
        (__attribute__((address_space(3))) unsigned int*)lds,
        16, 0, 0);
}

// ---------------------------------------------------------------------------
// Kernel 1: row L2-normalize + 2-term bf16 split + squared-norm-after-norm
// ---------------------------------------------------------------------------
__global__ __launch_bounds__(256) void k_norm_split(const float* __restrict__ in,
    unsigned short* __restrict__ hi, unsigned short* __restrict__ lo,
    float* __restrict__ sq)
{
    int row = blockIdx.x;
    int tid = threadIdx.x;
    const float4* rp = (const float4*)(in + (size_t)row * DIM);
    float4 v0 = rp[tid * 2 + 0];
    float4 v1 = rp[tid * 2 + 1];
    float ss = v0.x*v0.x + v0.y*v0.y + v0.z*v0.z + v0.w*v0.w
             + v1.x*v1.x + v1.y*v1.y + v1.z*v1.z + v1.w*v1.w;
    #pragma unroll
    for (int off = 32; off > 0; off >>= 1) ss += __shfl_down(ss, off, 64);
    __shared__ float wsum[4];
    __shared__ float s_den;
    if ((tid & 63) == 0) wsum[tid >> 6] = ss;
    __syncthreads();
    if (tid == 0) {
        float tot = wsum[0] + wsum[1] + wsum[2] + wsum[3];
        float den = fmaxf(sqrtf(tot), 1e-12f);
        s_den = den;
        sq[row] = tot / (den * den);
    }
    __syncthreads();
    float den = s_den;
    float xs[8];
    xs[0]=v0.x/den; xs[1]=v0.y/den; xs[2]=v0.z/den; xs[3]=v0.w/den;
    xs[4]=v1.x/den; xs[5]=v1.y/den; xs[6]=v1.z/den; xs[7]=v1.w/den;
    us8v hv, lv;
    #pragma unroll
    for (int j = 0; j < 8; ++j) {
        unsigned short h = f2bf(xs[j]);
        hv[j] = h;
        lv[j] = f2bf(xs[j] - bf2f(h));
    }
    *(us8v*)&hi[(size_t)row * DIM + tid * 8] = hv;
    *(us8v*)&lo[(size_t)row * DIM + tid * 8] = lv;
}

// ---------------------------------------------------------------------------
// Kernel 2: dual MFMA GEMM over split-bf16 operands, fused pdist epilogue.
// Swizzle s(row) = (row>>1)&3 on 16B chunks: bank-slot (4*(lr&1) + kc^s) & 7
// covers all 8 slots exactly 8 lanes each over the wave -> balanced (free).
// (Old (row&3) swizzle was a 4-way conflict: 3.78e7 SQ_LDS_BANK_CONFLICT.)
// ---------------------------------------------------------------------------
__global__ __launch_bounds__(256, 2) void k_gemm_mfma(
    const unsigned short* __restrict__ T1, const unsigned short* __restrict__ T2,
    const unsigned short* __restrict__ S1, const unsigned short* __restrict__ S2,
    const float* __restrict__ t2v, const float* __restrict__ s2v,
    float* __restrict__ distT, float* __restrict__ distS)
{
    __shared__ unsigned short As[128 * 32];   // 8 KB
    __shared__ unsigned short Bt[128 * 32];
    __shared__ unsigned short Bs[128 * 32];

    int tid = threadIdx.x;

    // bijective XCD-aware swizzle (nwg = 1024, divisible by 8)
    int orig  = blockIdx.y * gridDim.x + blockIdx.x;
    int nwg   = gridDim.x * gridDim.y;
    int cpx   = nwg >> 3;
    int swz   = (orig & 7) * cpx + (orig >> 3);
    int bx    = swz % gridDim.x;
    int by    = swz / gridDim.x;
    int m0 = by * 128, n0 = bx * 128;

    // staging: thread t covers row r0=t>>2, source chunk (t&3)^s(r0), s=(r>>1)&3
    // (s(64+r0)==s(r0) since 64>>1=32 == 0 mod 4, so same cs0 for both halves)
    int r0   = tid >> 2;                           // 0..63
    int cs0  = (((tid & 3) ^ ((r0 >> 1) & 3)) << 4);
    unsigned ldst = (unsigned)tid * 16;            // linear LDS dest

    // wave/fragment geometry
    int l  = tid & 63;
    int w  = tid >> 6;
    int wr = w >> 1, wc = w & 1;               // wave tile (2x2 of 64x64)
    int lr = l & 15;                           // fragment lane row/col
    int kc = l >> 4;                           // k-chunk 0..3 (8 bf16 each)

    f32x4 acc_t[4][4], acc_s[4][4];
    #pragma unroll
    for (int m = 0; m < 4; ++m)
        #pragma unroll
        for (int n = 0; n < 4; ++n) {
            acc_t[m][n] = (f32x4)0.0f;
            acc_s[m][n] = (f32x4)0.0f;
        }

    const unsigned short* segA[3]  = {T1, T1, T2};
    const unsigned short* segBt[3] = {T1, T2, T1};
    const unsigned short* segBs[3] = {S1, S2, S1};

    for (int seg = 0; seg < 3; ++seg) {
        const char* pA  = (const char*)segA[seg];
        const char* pBt = (const char*)segBt[seg];
        const char* pBs = (const char*)segBs[seg];
        for (int k0 = 0; k0 < DIM; k0 += 32) {
            size_t gA0 = ((size_t)(m0 + r0)      * DIM + k0) * 2 + cs0;
            size_t gA1 = ((size_t)(m0 + 64 + r0) * DIM + k0) * 2 + cs0;
            size_t gB0 = ((size_t)(n0 + r0)      * DIM + k0) * 2 + cs0;
            size_t gB1 = ((size_t)(n0 + 64 + r0) * DIM + k0) * 2 + cs0;
            gload16(pA  + gA0, (char*)As + ldst);
            gload16(pA  + gA1, (char*)As + 4096 + ldst);
            gload16(pBt + gB0, (char*)Bt + ldst);
            gload16(pBt + gB1, (char*)Bt + 4096 + ldst);
            gload16(pBs + gB0, (char*)Bs + ldst);
            gload16(pBs + gB1, (char*)Bs + 4096 + ldst);
            __syncthreads();

            bf16x8 a[4], btf[4], bsf[4];
            #pragma unroll
            for (int m = 0; m < 4; ++m) {
                int ra = wr * 64 + m * 16 + lr;
                int co = ((kc ^ ((ra >> 1) & 3)) << 4);
                a[m] = *(const bf16x8*)((const char*)As + ra * 64 + co);
            }
            #pragma unroll
            for (int n = 0; n < 4; ++n) {
                int rb = wc * 64 + n * 16 + lr;
                int co = ((kc ^ ((rb >> 1) & 3)) << 4);
                btf[n] = *(const bf16x8*)((const char*)Bt + rb * 64 + co);
                bsf[n] = *(const bf16x8*)((const char*)Bs + rb * 64 + co);
            }
            #pragma unroll
            for (int m = 0; m < 4; ++m)
                #pragma unroll
                for (int n = 0; n < 4; ++n) {
                    acc_t[m][n] = __builtin_amdgcn_mfma_f32_16x16x32_bf16(
                        a[m], btf[n], acc_t[m][n], 0, 0, 0);
                    acc_s[m][n] = __builtin_amdgcn_mfma_f32_16x16x32_bf16(
                        a[m], bsf[n], acc_s[m][n], 0, 0, 0);
                }
            __syncthreads();
        }
    }

    // epilogue: dist = sqrt(max(a2_row + b2_col - 2*dot, 1e-12))
    // C/D layout (m89): col = lane&15, row = (lane>>4)*4 + reg
    int colb = n0 + wc * 64 + lr;
    int rowb = m0 + wr * 64 + (kc << 2);
    float t2row[4][4];
    #pragma unroll
    for (int m = 0; m < 4; ++m)
        #pragma unroll
        for (int r = 0; r < 4; ++r) t2row[m][r] = t2v[rowb + m * 16 + r];
    #pragma unroll
    for (int n = 0; n < 4; ++n) {
        int col = colb + n * 16;
        float t2c = t2v[col];
        float s2c = s2v[col];
        #pragma unroll
        for (int m = 0; m < 4; ++m) {
            f32x4 ct = acc_t[m][n];
            f32x4 cs = acc_s[m][n];
            int row = rowb + m * 16;
            #pragma unroll
            for (int r = 0; r < 4; ++r) {
                size_t o = (size_t)(row + r) * NROW + col;
                distT[o] = sqrtf(fmaxf(t2row[m][r] + t2c - 2.0f * ct[r], 1e-12f));
                distS[o] = sqrtf(fmaxf(t2row[m][r] + s2c - 2.0f * cs[r], 1e-12f));
            }
        }
    }
}

// ---------------------------------------------------------------------------
// Kernel 3: per-row mining, register-resident. One block (256 thr) per row.
// Thread owns 16 CONTIGUOUS elements (j = tid*16 + q) so thread order ==
// index order (needed for exact ordinal selection within equal-value group).
// ---------------------------------------------------------------------------
__device__ inline float pair_term(float an_v, float ap_v, float an_t, float ap_t)
{
    float w_an = fmaxf(an_t - an_v, 0.f);
    float w_ap = fmaxf(ap_v - ap_t, 0.f);
    float l0 = w_an * an_v / 0.04f;
    float l1 = w_ap * ap_v / 0.04f;
    float mx = fmaxf(l0, l1);
    return mx + logf(expf(l0 - mx) + expf(l1 - mx)) - l0;
}

__device__ __forceinline__ unsigned long long wred_min64(unsigned long long v) {
    #pragma unroll
    for (int o = 32; o > 0; o >>= 1) {
        unsigned long long x = __shfl_down(v, o, 64);
        v = (x < v) ? x : v;
    }
    return v;
}
__device__ __forceinline__ unsigned long long wred_max64(unsigned long long v) {
    #pragma unroll
    for (int o = 32; o > 0; o >>= 1) {
        unsigned long long x = __shfl_down(v, o, 64);
        v = (x > v) ? x : v;
    }
    return v;
}

// radix-select rank-th smallest (0-based) among class elements; returns exact
// value and the index with argsort-stable ordinal semantics.
__device__ void radix_select_reg(const unsigned u[16], unsigned negbits,
                                 unsigned selNeg, int rank,
                                 unsigned* hist, unsigned* s_wt, unsigned* s_sel,
                                 int tid, float& val, int& idx)
{
    unsigned prefix = 0;
    int r = rank;
    #pragma unroll
    for (int pass = 0; pass < 4; ++pass) {
        const int shift = 24 - pass * 8;
        hist[tid] = 0;
        __syncthreads();
        // run-length aggregated histogram atomics (keys cluster by exponent)
        {
            unsigned curbin = 0xFFFFFFFFu, rl = 0;
            #pragma unroll
            for (int q = 0; q < 16; ++q) {
                unsigned key = (((negbits >> q) & 1u) == selNeg) ? u[q] : 0xFFFFFFFFu;
                bool match = (pass == 0) || ((key >> (shift + 8)) == (prefix >> (shift + 8)));
                if (match) {
                    unsigned b = (key >> shift) & 255u;
                    if (b == curbin) { rl++; }
                    else {
                        if (rl) atomicAdd(&hist[curbin], rl);
                        curbin = b; rl = 1;
                    }
                }
            }
            if (rl) atomicAdd(&hist[curbin], rl);
        }
        __syncthreads();
        // parallel prefix over 256 bins (wave scan + cross-wave offsets)
        unsigned h = hist[tid];
        unsigned incl = h;
        #pragma unroll
        for (int o = 1; o < 64; o <<= 1) {
            unsigned x = __shfl_up(incl, o, 64);
            if ((tid & 63) >= o) incl += x;
        }
        if ((tid & 63) == 63) s_wt[tid >> 6] = incl;
        __syncthreads();
        int wv = tid >> 6;
        unsigned base = 0;
        if (wv > 0) base += s_wt[0];
        if (wv > 1) base += s_wt[1];
        if (wv > 2) base += s_wt[2];
        incl += base;
        unsigned excl = incl - h;
        if ((unsigned)r >= excl && (unsigned)r < incl) {
            s_sel[0] = (unsigned)tid;
            s_sel[1] = (unsigned)r - excl;
        }
        __syncthreads();
        prefix |= s_sel[0] << shift;
        r = (int)s_sel[1];
        __syncthreads();
    }
    // r = ordinal within the equal-value group; pick the r-th match by index.
    {
        unsigned cnt = 0;
        #pragma unroll
        for (int q = 0; q < 16; ++q) {
            unsigned key = (((negbits >> q) & 1u) == selNeg) ? u[q] : 0xFFFFFFFFu;
            if (key == prefix) cnt++;
        }
        hist[tid] = cnt;
        __syncthreads();
        unsigned incl = hist[tid];
        #pragma unroll
        for (int o = 1; o < 64; o <<= 1) {
            unsigned x = __shfl_up(incl, o, 64);
            if ((tid & 63) >= o) incl += x;
        }
        if ((tid & 63) == 63) s_wt[tid >> 6] = incl;
        __syncthreads();
        int wv = tid >> 6;
        unsigned base = 0;
        if (wv > 0) base += s_wt[0];
        if (wv > 1) base += s_wt[1];
        if (wv > 2) base += s_wt[2];
        incl += base;
        unsigned excl = incl - cnt;
        if ((unsigned)r >= excl && (unsigned)r < incl) {
            int need = r - (int)excl;
            #pragma unroll
            for (int q = 0; q < 16; ++q) {   // ascending j within thread
                unsigned key = (((negbits >> q) & 1u) == selNeg) ? u[q] : 0xFFFFFFFFu;
                if (key == prefix) {
                    if (need == 0) { s_sel[0] = (unsigned)(tid * 16 + q); }
                    need--;
                }
            }
        }
        __syncthreads();
    }
    val = __uint_as_float(prefix);
    idx = (int)s_sel[0];
    __syncthreads();
}

__global__ __launch_bounds__(256) void k_rowstats(const float* __restrict__ distS,
    const float* __restrict__ distT, float* __restrict__ terms)
{
    __shared__ unsigned hist[256];
    __shared__ unsigned s_wt[4];
    __shared__ unsigned s_sel[2];
    __shared__ unsigned long long s_red[4][4];
    __shared__ int s_cw[4];
    __shared__ float s_t1;

    int i = blockIdx.x, tid = threadIdx.x;
    const float* dSrow = distS + (size_t)i * NROW;
    const float* dTrow = distT + (size_t)i * NROW;

    if (tid == 0) s_t1 = dSrow[i];   // temp1 = dist[i,i]

    // blocked ownership: elements j = tid*16 .. tid*16+15
    float4 dv[4], tv[4];
    #pragma unroll
    for (int c = 0; c < 4; ++c) {
        dv[c] = *(const float4*)(dSrow + tid * 16 + c * 4);
        tv[c] = *(const float4*)(dTrow + tid * 16 + c * 4);
    }
    __syncthreads();
    float temp1 = s_t1;

    unsigned u[16];
    unsigned negbits = 0;
    #pragma unroll
    for (int c = 0; c < 4; ++c) {
        const float* dp = (const float*)&dv[c];
        const float* tp = (const float*)&tv[c];
        #pragma unroll
        for (int k = 0; k < 4; ++k) {
            int q = c * 4 + k;
            u[q] = __float_as_uint(dp[k]);
            if (tp[k] > temp1) negbits |= (1u << q);
        }
    }

    // mining passes in uint domain (d >= 0 so float order == uint order)
    unsigned long long Pan  = ~0ull;  // min (neg? u : BIG)
    unsigned long long Pap  = 0ull;   // max (neg? 0 : u)
    unsigned long long Pane = 0ull;   // max (neg? u : 0)
    unsigned long long Pape = ~0ull;  // min (neg? BIG : u)
    int cnt = 0;
    #pragma unroll
    for (int q = 0; q < 16; ++q) {
        unsigned j = (unsigned)(tid * 16 + q);
        unsigned neg = (negbits >> q) & 1u;
        cnt += (int)neg;
        unsigned kan  = neg ? u[q] : BIGU;
        unsigned kap  = neg ? 0u   : u[q];
        unsigned kane = neg ? u[q] : 0u;
        unsigned kape = neg ? BIGU : u[q];
        unsigned long long pan  = ((unsigned long long)kan  << 32) | j;
        unsigned long long pap  = ((unsigned long long)kap  << 32) | (0xFFFFFFFFu - j);
        unsigned long long pane = ((unsigned long long)kane << 32) | (0xFFFFFFFFu - j);
        unsigned long long pape = ((unsigned long long)kape << 32) | j;
        if (pan  < Pan)  Pan  = pan;
        if (pap  > Pap)  Pap  = pap;
        if (pane > Pane) Pane = pane;
        if (pape < Pape) Pape = pape;
    }
    Pan  = wred_min64(Pan);
    Pap  = wred_max64(Pap);
    Pane = wred_max64(Pane);
    Pape = wred_min64(Pape);
    #pragma unroll
    for (int o = 32; o > 0; o >>= 1) cnt += __shfl_down(cnt, o, 64);
    if ((tid & 63) == 0) {
        int wv = tid >> 6;
        s_red[0][wv] = Pan; s_red[1][wv] = Pap;
        s_red[2][wv] = Pane; s_red[3][wv] = Pape;
        s_cw[wv] = cnt;
    }
    __syncthreads();
    unsigned long long Ran = ~0ull, Rap = 0ull, Rane = 0ull, Rape = ~0ull;
    #pragma unroll
    for (int wv = 0; wv < 4; ++wv) {
        if (s_red[0][wv] < Ran)  Ran  = s_red[0][wv];
        if (s_red[1][wv] > Rap)  Rap  = s_red[1][wv];
        if (s_red[2][wv] > Rane) Rane = s_red[2][wv];
        if (s_red[3][wv] < Rape) Rape = s_red[3][wv];
    }
    int k_neg = s_cw[0] + s_cw[1] + s_cw[2] + s_cw[3];
    int k_pos = NROW - k_neg;

    float an_v  = __uint_as_float((unsigned)(Ran  >> 32)); int an_i  = (int)(Ran & 0xFFFFFFFFull);
    float ap_v  = __uint_as_float((unsigned)(Rap  >> 32)); int ap_i  = (int)(0xFFFFFFFFu - (unsigned)(Rap & 0xFFFFFFFFull));
    float ane_v = __uint_as_float((unsigned)(Rane >> 32)); int ane_i = (int)(0xFFFFFFFFu - (unsigned)(Rane & 0xFFFFFFFFull));
    float ape_v = __uint_as_float((unsigned)(Rape >> 32)); int ape_i = (int)(Rape & 0xFFFFFFFFull);

    __syncthreads();   // protect s_red/s_cw before hist reuse

    float mn_v; int mn_i;
    if (k_neg > 0) {
        radix_select_reg(u, negbits, 1u, (k_neg - 1) >> 1, hist, s_wt, s_sel, tid, mn_v, mn_i);
    } else { mn_v = 0.f; mn_i = 0; }
    float mp_v; int mp_i;
    if (k_pos > 0) {
        radix_select_reg(u, negbits, 0u, (k_pos - 1) >> 1, hist, s_wt, s_sel, tid, mp_v, mp_i);
    } else { mp_v = 0.f; mp_i = 0; }

    if (tid == 0) {
        float an_t  = dTrow[an_i];
        float ap_t  = dTrow[ap_i];
        float ane_t = dTrow[ane_i];
        float ape_t = dTrow[ape_i];
        float mn_t  = dTrow[mn_i];
        float mp_t  = dTrow[mp_i];
        terms[i]            = pair_term(an_v,  ap_v,  an_t,  ap_t);   // d-branch
        terms[NROW + i]     = pair_term(ane_v, ape_v, ane_t, ape_t);  // e-branch
        terms[2*NROW + i]   = pair_term(mn_v,  mp_v,  mn_t,  mp_t);   // m-branch
    }
}

// ---------------------------------------------------------------------------
// Kernel 4: deterministic final reduction + decay weights from epoch.
// ---------------------------------------------------------------------------
__global__ __launch_bounds__(256) void k_finalize(const float* __restrict__ terms,
    const void* __restrict__ epoch_p, float* __restrict__ out)
{
    __shared__ float red[256];
    int tid = threadIdx.x;
    float s0 = 0.f, s1 = 0.f, s2 = 0.f;
    for (int j = tid; j < NROW; j += 256) {
        s0 += terms[j];
        s1 += terms[NROW + j];
        s2 += terms[2*NROW + j];
    }
    float tot[3];
    float sv[3] = {s0, s1, s2};
    for (int t = 0; t < 3; ++t) {
        red[tid] = sv[t];
        __syncthreads();
        for (int st = 128; st > 0; st >>= 1) {
            if (tid < st) red[tid] += red[tid + st];
            __syncthreads();
        }
        tot[t] = red[0];
        __syncthreads();
    }
    if (tid == 0) {
        int ei = *(const int*)epoch_p;
        double step;
        if (ei >= 0 && ei < 100000) step = (double)ei;
        else step = (double)(*(const float*)epoch_p);
        const double PI = 3.14159265358979323846;
        double de = 0.5 * 0.75 * (1.0 + cos(PI * step / 120.0));
        double dm = 0.5 * 0.75 * (1.0 + cos(PI * step / 240.0));
        double e = (step < 120.0) ? de : 0.0;
        double m = dm;
        double d = 3.0 - e - m;
        double loss_d = (double)tot[0] / (double)NROW;
        double loss_e = (double)tot[1] / (double)NROW;
        double loss_m = (double)tot[2] / (double)NROW;
        out[0] = (float)(loss_e * e + loss_m * m + loss_d * d);
    }
}

// ---------------------------------------------------------------------------
extern "C" void kernel_launch(void* const* d_in, const int* in_sizes, int n_in,
                              void* d_out, int out_size, void* d_ws, size_t ws_size,
                              hipStream_t stream)
{
    (void)in_sizes; (void)n_in; (void)out_size; (void)ws_size;
    const float* t_in = (const float*)d_in[0];
    const float* s_in = (const float*)d_in[1];
    const void*  epoch = d_in[2];
    float* out = (float*)d_out;

    char* ws = (char*)d_ws;
    size_t off = 0;
    unsigned short* T1 = (unsigned short*)(ws + off); off += (size_t)NROW * DIM * 2;
    unsigned short* T2 = (unsigned short*)(ws + off); off += (size_t)NROW * DIM * 2;
    unsigned short* S1 = (unsigned short*)(ws + off); off += (size_t)NROW * DIM * 2;
    unsigned short* S2 = (unsigned short*)(ws + off); off += (size_t)NROW * DIM * 2;
    float* t2v   = (float*)(ws + off); off += (size_t)NROW * 4;
    float* s2v   = (float*)(ws + off); off += (size_t)NROW * 4;
    float* distT = (float*)(ws + off); off += (size_t)NROW * NROW * 4;
    float* distS = (float*)(ws + off); off += (size_t)NROW * NROW * 4;
    float* terms = (float*)(ws + off); off += (size_t)3 * NROW * 4;

    k_norm_split<<<NROW, 256, 0, stream>>>(t_in, T1, T2, t2v);
    k_norm_split<<<NROW, 256, 0, stream>>>(s_in, S1, S2, s2v);
    k_gemm_mfma<<<dim3(32, 32), 256, 0, stream>>>(T1, T2, S1, S2, t2v, s2v, distT, distS);
    k_rowstats<<<NROW, 256, 0, stream>>>(distS, distT, terms);
    k_finalize<<<1, 256, 0, stream>>>(terms, epoch, out);
}

// Round 6
// 668.553 us; speedup vs baseline: 1.4796x; 1.0157x over previous
//
#include <hip/hip_runtime.h>
#include <math.h>
#include <cfloat>
#include <climits>

#define NROW 4096
#define DIM  2048
#define BIGF 100000.0f
#define BIGU 0x47C35000u   // bits of 100000.0f

typedef float  f32x4  __attribute__((ext_vector_type(4)));
typedef __bf16 bf16x8 __attribute__((ext_vector_type(8)));
typedef unsigned short us8v __attribute__((ext_vector_type(8)));

// ---------------------------------------------------------------------------
// bf16 helpers (RNE)
// ---------------------------------------------------------------------------
__device__ __forceinline__ unsigned short f2bf(float x) {
    unsigned u = __float_as_uint(x);
    u += 0x7fffu + ((u >> 16) & 1u);
    return (unsigned short)(u >> 16);
}
__device__ __forceinline__ float bf2f(unsigned short h) {
    return __uint_as_float(((unsigned)h) << 16);
}

// async global->LDS, 16B per lane (dest linear: wave-uniform base + lane*16)
__device__ __forceinline__ void gload16(const void* g, void* lds) {
    __builtin_amdgcn_global_load_lds(
        (const __attribute__((address_space(1))) unsigned int*)g,
        (__attribute__((address_space(3))) unsigned int*)lds,
        16, 0, 0);
}

// ---------------------------------------------------------------------------
// Kernel 1: row L2-normalize + 2-term bf16 split + squared-norm-after-norm
// ---------------------------------------------------------------------------
__global__ __launch_bounds__(256) void k_norm_split(const float* __restrict__ in,
    unsigned short* __restrict__ hi, unsigned short* __restrict__ lo,
    float* __restrict__ sq)
{
    int row = blockIdx.x;
    int tid = threadIdx.x;
    const float4* rp = (const float4*)(in + (size_t)row * DIM);
    float4 v0 = rp[tid * 2 + 0];
    float4 v1 = rp[tid * 2 + 1];
    float ss = v0.x*v0.x + v0.y*v0.y + v0.z*v0.z + v0.w*v0.w
             + v1.x*v1.x + v1.y*v1.y + v1.z*v1.z + v1.w*v1.w;
    #pragma unroll
    for (int off = 32; off > 0; off >>= 1) ss += __shfl_down(ss, off, 64);
    __shared__ float wsum[4];
    __shared__ float s_den;
    if ((tid & 63) == 0) wsum[tid >> 6] = ss;
    __syncthreads();
    if (tid == 0) {
        float tot = wsum[0] + wsum[1] + wsum[2] + wsum[3];
        float den = fmaxf(sqrtf(tot), 1e-12f);
        s_den = den;
        sq[row] = tot / (den * den);
    }
    __syncthreads();
    float den = s_den;
    float xs[8];
    xs[0]=v0.x/den; xs[1]=v0.y/den; xs[2]=v0.z/den; xs[3]=v0.w/den;
    xs[4]=v1.x/den; xs[5]=v1.y/den; xs[6]=v1.z/den; xs[7]=v1.w/den;
    us8v hv, lv;
    #pragma unroll
    for (int j = 0; j < 8; ++j) {
        unsigned short h = f2bf(xs[j]);
        hv[j] = h;
        lv[j] = f2bf(xs[j] - bf2f(h));
    }
    *(us8v*)&hi[(size_t)row * DIM + tid * 8] = hv;
    *(us8v*)&lo[(size_t)row * DIM + tid * 8] = lv;
}

// ---------------------------------------------------------------------------
// Kernel 2: dual MFMA GEMM, 2-phase software pipeline (T3 minimum recipe):
// double-buffered LDS (2 x 24KB), stage(t+1) issued BEFORE compute(t), ONE
// __syncthreads per K-step (its vmcnt(0)+lgkmcnt(0) drain IS the recipe's
// "vmcnt(0); barrier"). Loads get the ~620-cycle MFMA window to fly instead
// of being drained right after issue (the old ~47% idle at 2 blocks/CU).
// Swizzle s(row)=(row>>1)&3 on 16B chunks (bank-conflict 0, verified R5).
// ---------------------------------------------------------------------------
__global__ __launch_bounds__(256, 2) void k_gemm_mfma(
    const unsigned short* __restrict__ T1, const unsigned short* __restrict__ T2,
    const unsigned short* __restrict__ S1, const unsigned short* __restrict__ S2,
    const float* __restrict__ t2v, const float* __restrict__ s2v,
    float* __restrict__ distT, float* __restrict__ distS)
{
    // buf layout: [As 8KB][Bt 8KB][Bs 8KB], two buffers = 48KB
    __shared__ __align__(16) unsigned char smem[2][24576];

    int tid = threadIdx.x;

    // bijective XCD-aware swizzle (nwg = 1024, divisible by 8)
    int orig  = blockIdx.y * gridDim.x + blockIdx.x;
    int nwg   = gridDim.x * gridDim.y;
    int cpx   = nwg >> 3;
    int swz   = (orig & 7) * cpx + (orig >> 3);
    int bx    = swz % gridDim.x;
    int by    = swz / gridDim.x;
    int m0 = by * 128, n0 = bx * 128;

    // staging: thread t covers row r0=t>>2, source chunk (t&3)^s(r0), s=(r>>1)&3
    int r0   = tid >> 2;                           // 0..63
    int cs0  = (((tid & 3) ^ ((r0 >> 1) & 3)) << 4);
    unsigned ldst = (unsigned)tid * 16;            // linear LDS dest

    // wave/fragment geometry
    int l  = tid & 63;
    int w  = tid >> 6;
    int wr = w >> 1, wc = w & 1;               // wave tile (2x2 of 64x64)
    int lr = l & 15;                           // fragment lane row/col
    int kc = l >> 4;                           // k-chunk 0..3 (8 bf16 each)

    f32x4 acc_t[4][4], acc_s[4][4];
    #pragma unroll
    for (int m = 0; m < 4; ++m)
        #pragma unroll
        for (int n = 0; n < 4; ++n) {
            acc_t[m][n] = (f32x4)0.0f;
            acc_s[m][n] = (f32x4)0.0f;
        }

    const int NT = 192;   // 3 segments x 64 K-steps, flattened

    auto stage = [&](int tt, unsigned char* base) {
        int sg = tt >> 6;                         // 0..2 (uniform)
        int k0 = (tt & 63) << 5;
        // seg 0: A=T1 Bt=T1 Bs=S1 | seg 1: A=T1 Bt=T2 Bs=S2 | seg 2: A=T2 Bt=T1 Bs=S1
        const char* pA  = (const char*)((sg == 2) ? T2 : T1);
        const char* pBt = (const char*)((sg == 1) ? T2 : T1);
        const char* pBs = (const char*)((sg == 1) ? S2 : S1);
        size_t gA0 = ((size_t)(m0 + r0)      * DIM + k0) * 2 + cs0;
        size_t gA1 = ((size_t)(m0 + 64 + r0) * DIM + k0) * 2 + cs0;
        size_t gB0 = ((size_t)(n0 + r0)      * DIM + k0) * 2 + cs0;
        size_t gB1 = ((size_t)(n0 + 64 + r0) * DIM + k0) * 2 + cs0;
        gload16(pA  + gA0, base + ldst);
        gload16(pA  + gA1, base + 4096  + ldst);
        gload16(pBt + gB0, base + 8192  + ldst);
        gload16(pBt + gB1, base + 12288 + ldst);
        gload16(pBs + gB0, base + 16384 + ldst);
        gload16(pBs + gB1, base + 20480 + ldst);
    };

    // prologue: fill buffer 0 (syncthreads drains vmcnt before first read)
    stage(0, smem[0]);
    __syncthreads();

    int cur = 0;
    for (int t = 0; t < NT; ++t) {
        // phase 1: issue next tile's loads into the other buffer
        if (t + 1 < NT) stage(t + 1, smem[cur ^ 1]);

        // phase 2: compute current tile from buf[cur]
        const unsigned char* base = smem[cur];
        bf16x8 a[4], btf[4], bsf[4];
        #pragma unroll
        for (int m = 0; m < 4; ++m) {
            int ra = wr * 64 + m * 16 + lr;
            int co = ((kc ^ ((ra >> 1) & 3)) << 4);
            a[m] = *(const bf16x8*)(base + ra * 64 + co);
        }
        #pragma unroll
        for (int n = 0; n < 4; ++n) {
            int rb = wc * 64 + n * 16 + lr;
            int co = ((kc ^ ((rb >> 1) & 3)) << 4);
            btf[n] = *(const bf16x8*)(base + 8192  + rb * 64 + co);
            bsf[n] = *(const bf16x8*)(base + 16384 + rb * 64 + co);
        }
        #pragma unroll
        for (int m = 0; m < 4; ++m)
            #pragma unroll
            for (int n = 0; n < 4; ++n) {
                acc_t[m][n] = __builtin_amdgcn_mfma_f32_16x16x32_bf16(
                    a[m], btf[n], acc_t[m][n], 0, 0, 0);
                acc_s[m][n] = __builtin_amdgcn_mfma_f32_16x16x32_bf16(
                    a[m], bsf[n], acc_s[m][n], 0, 0, 0);
            }

        // one barrier per K-step: drains vmcnt(0) (next tile staged) and
        // guarantees all waves done reading buf[cur] before it's overwritten.
        __syncthreads();
        cur ^= 1;
    }

    // epilogue: dist = sqrt(max(a2_row + b2_col - 2*dot, 1e-12))
    // C/D layout (m89): col = lane&15, row = (lane>>4)*4 + reg
    int colb = n0 + wc * 64 + lr;
    int rowb = m0 + wr * 64 + (kc << 2);
    float t2row[4][4];
    #pragma unroll
    for (int m = 0; m < 4; ++m)
        #pragma unroll
        for (int r = 0; r < 4; ++r) t2row[m][r] = t2v[rowb + m * 16 + r];
    #pragma unroll
    for (int n = 0; n < 4; ++n) {
        int col = colb + n * 16;
        float t2c = t2v[col];
        float s2c = s2v[col];
        #pragma unroll
        for (int m = 0; m < 4; ++m) {
            f32x4 ct = acc_t[m][n];
            f32x4 cs = acc_s[m][n];
            int row = rowb + m * 16;
            #pragma unroll
            for (int r = 0; r < 4; ++r) {
                size_t o = (size_t)(row + r) * NROW + col;
                distT[o] = sqrtf(fmaxf(t2row[m][r] + t2c - 2.0f * ct[r], 1e-12f));
                distS[o] = sqrtf(fmaxf(t2row[m][r] + s2c - 2.0f * cs[r], 1e-12f));
            }
        }
    }
}

// ---------------------------------------------------------------------------
// Kernel 3: per-row mining, register-resident. One block (256 thr) per row.
// Thread owns 16 CONTIGUOUS elements (j = tid*16 + q) so thread order ==
// index order (needed for exact ordinal selection within equal-value group).
// ---------------------------------------------------------------------------
__device__ inline float pair_term(float an_v, float ap_v, float an_t, float ap_t)
{
    float w_an = fmaxf(an_t - an_v, 0.f);
    float w_ap = fmaxf(ap_v - ap_t, 0.f);
    float l0 = w_an * an_v / 0.04f;
    float l1 = w_ap * ap_v / 0.04f;
    float mx = fmaxf(l0, l1);
    return mx + logf(expf(l0 - mx) + expf(l1 - mx)) - l0;
}

__device__ __forceinline__ unsigned long long wred_min64(unsigned long long v) {
    #pragma unroll
    for (int o = 32; o > 0; o >>= 1) {
        unsigned long long x = __shfl_down(v, o, 64);
        v = (x < v) ? x : v;
    }
    return v;
}
__device__ __forceinline__ unsigned long long wred_max64(unsigned long long v) {
    #pragma unroll
    for (int o = 32; o > 0; o >>= 1) {
        unsigned long long x = __shfl_down(v, o, 64);
        v = (x > v) ? x : v;
    }
    return v;
}

// radix-select rank-th smallest (0-based) among class elements; returns exact
// value and the index with argsort-stable ordinal semantics.
__device__ void radix_select_reg(const unsigned u[16], unsigned negbits,
                                 unsigned selNeg, int rank,
                                 unsigned* hist, unsigned* s_wt, unsigned* s_sel,
                                 int tid, float& val, int& idx)
{
    unsigned prefix = 0;
    int r = rank;
    #pragma unroll
    for (int pass = 0; pass < 4; ++pass) {
        const int shift = 24 - pass * 8;
        hist[tid] = 0;
        __syncthreads();
        // run-length aggregated histogram atomics (keys cluster by exponent)
        {
            unsigned curbin = 0xFFFFFFFFu, rl = 0;
            #pragma unroll
            for (int q = 0; q < 16; ++q) {
                unsigned key = (((negbits >> q) & 1u) == selNeg) ? u[q] : 0xFFFFFFFFu;
                bool match = (pass == 0) || ((key >> (shift + 8)) == (prefix >> (shift + 8)));
                if (match) {
                    unsigned b = (key >> shift) & 255u;
                    if (b == curbin) { rl++; }
                    else {
                        if (rl) atomicAdd(&hist[curbin], rl);
                        curbin = b; rl = 1;
                    }
                }
            }
            if (rl) atomicAdd(&hist[curbin], rl);
        }
        __syncthreads();
        // parallel prefix over 256 bins (wave scan + cross-wave offsets)
        unsigned h = hist[tid];
        unsigned incl = h;
        #pragma unroll
        for (int o = 1; o < 64; o <<= 1) {
            unsigned x = __shfl_up(incl, o, 64);
            if ((tid & 63) >= o) incl += x;
        }
        if ((tid & 63) == 63) s_wt[tid >> 6] = incl;
        __syncthreads();
        int wv = tid >> 6;
        unsigned base = 0;
        if (wv > 0) base += s_wt[0];
        if (wv > 1) base += s_wt[1];
        if (wv > 2) base += s_wt[2];
        incl += base;
        unsigned excl = incl - h;
        if ((unsigned)r >= excl && (unsigned)r < incl) {
            s_sel[0] = (unsigned)tid;
            s_sel[1] = (unsigned)r - excl;
        }
        __syncthreads();
        prefix |= s_sel[0] << shift;
        r = (int)s_sel[1];
        __syncthreads();
    }
    // r = ordinal within the equal-value group; pick the r-th match by index.
    {
        unsigned cnt = 0;
        #pragma unroll
        for (int q = 0; q < 16; ++q) {
            unsigned key = (((negbits >> q) & 1u) == selNeg) ? u[q] : 0xFFFFFFFFu;
            if (key == prefix) cnt++;
        }
        hist[tid] = cnt;
        __syncthreads();
        unsigned incl = hist[tid];
        #pragma unroll
        for (int o = 1; o < 64; o <<= 1) {
            unsigned x = __shfl_up(incl, o, 64);
            if ((tid & 63) >= o) incl += x;
        }
        if ((tid & 63) == 63) s_wt[tid >> 6] = incl;
        __syncthreads();
        int wv = tid >> 6;
        unsigned base = 0;
        if (wv > 0) base += s_wt[0];
        if (wv > 1) base += s_wt[1];
        if (wv > 2) base += s_wt[2];
        incl += base;
        unsigned excl = incl - cnt;
        if ((unsigned)r >= excl && (unsigned)r < incl) {
            int need = r - (int)excl;
            #pragma unroll
            for (int q = 0; q < 16; ++q) {   // ascending j within thread
                unsigned key = (((negbits >> q) & 1u) == selNeg) ? u[q] : 0xFFFFFFFFu;
                if (key == prefix) {
                    if (need == 0) { s_sel[0] = (unsigned)(tid * 16 + q); }
                    need--;
                }
            }
        }
        __syncthreads();
    }
    val = __uint_as_float(prefix);
    idx = (int)s_sel[0];
    __syncthreads();
}

__global__ __launch_bounds__(256) void k_rowstats(const float* __restrict__ distS,
    const float* __restrict__ distT, float* __restrict__ terms)
{
    __shared__ unsigned hist[256];
    __shared__ unsigned s_wt[4];
    __shared__ unsigned s_sel[2];
    __shared__ unsigned long long s_red[4][4];
    __shared__ int s_cw[4];
    __shared__ float s_t1;

    int i = blockIdx.x, tid = threadIdx.x;
    const float* dSrow = distS + (size_t)i * NROW;
    const float* dTrow = distT + (size_t)i * NROW;

    if (tid == 0) s_t1 = dSrow[i];   // temp1 = dist[i,i]

    // blocked ownership: elements j = tid*16 .. tid*16+15
    float4 dv[4], tv[4];
    #pragma unroll
    for (int c = 0; c < 4; ++c) {
        dv[c] = *(const float4*)(dSrow + tid * 16 + c * 4);
        tv[c] = *(const float4*)(dTrow + tid * 16 + c * 4);
    }
    __syncthreads();
    float temp1 = s_t1;

    unsigned u[16];
    unsigned negbits = 0;
    #pragma unroll
    for (int c = 0; c < 4; ++c) {
        const float* dp = (const float*)&dv[c];
        const float* tp = (const float*)&tv[c];
        #pragma unroll
        for (int k = 0; k < 4; ++k) {
            int q = c * 4 + k;
            u[q] = __float_as_uint(dp[k]);
            if (tp[k] > temp1) negbits |= (1u << q);
        }
    }

    // mining passes in uint domain (d >= 0 so float order == uint order)
    unsigned long long Pan  = ~0ull;  // min (neg? u : BIG)
    unsigned long long Pap  = 0ull;   // max (neg? 0 : u)
    unsigned long long Pane = 0ull;   // max (neg? u : 0)
    unsigned long long Pape = ~0ull;  // min (neg? BIG : u)
    int cnt = 0;
    #pragma unroll
    for (int q = 0; q < 16; ++q) {
        unsigned j = (unsigned)(tid * 16 + q);
        unsigned neg = (negbits >> q) & 1u;
        cnt += (int)neg;
        unsigned kan  = neg ? u[q] : BIGU;
        unsigned kap  = neg ? 0u   : u[q];
        unsigned kane = neg ? u[q] : 0u;
        unsigned kape = neg ? BIGU : u[q];
        unsigned long long pan  = ((unsigned long long)kan  << 32) | j;
        unsigned long long pap  = ((unsigned long long)kap  << 32) | (0xFFFFFFFFu - j);
        unsigned long long pane = ((unsigned long long)kane << 32) | (0xFFFFFFFFu - j);
        unsigned long long pape = ((unsigned long long)kape << 32) | j;
        if (pan  < Pan)  Pan  = pan;
        if (pap  > Pap)  Pap  = pap;
        if (pane > Pane) Pane = pane;
        if (pape < Pape) Pape = pape;
    }
    Pan  = wred_min64(Pan);
    Pap  = wred_max64(Pap);
    Pane = wred_max64(Pane);
    Pape = wred_min64(Pape);
    #pragma unroll
    for (int o = 32; o > 0; o >>= 1) cnt += __shfl_down(cnt, o, 64);
    if ((tid & 63) == 0) {
        int wv = tid >> 6;
        s_red[0][wv] = Pan; s_red[1][wv] = Pap;
        s_red[2][wv] = Pane; s_red[3][wv] = Pape;
        s_cw[wv] = cnt;
    }
    __syncthreads();
    unsigned long long Ran = ~0ull, Rap = 0ull, Rane = 0ull, Rape = ~0ull;
    #pragma unroll
    for (int wv = 0; wv < 4; ++wv) {
        if (s_red[0][wv] < Ran)  Ran  = s_red[0][wv];
        if (s_red[1][wv] > Rap)  Rap  = s_red[1][wv];
        if (s_red[2][wv] > Rane) Rane = s_red[2][wv];
        if (s_red[3][wv] < Rape) Rape = s_red[3][wv];
    }
    int k_neg = s_cw[0] + s_cw[1] + s_cw[2] + s_cw[3];
    int k_pos = NROW - k_neg;

    float an_v  = __uint_as_float((unsigned)(Ran  >> 32)); int an_i  = (int)(Ran & 0xFFFFFFFFull);
    float ap_v  = __uint_as_float((unsigned)(Rap  >> 32)); int ap_i  = (int)(0xFFFFFFFFu - (unsigned)(Rap & 0xFFFFFFFFull));
    float ane_v = __uint_as_float((unsigned)(Rane >> 32)); int ane_i = (int)(0xFFFFFFFFu - (unsigned)(Rane & 0xFFFFFFFFull));
    float ape_v = __uint_as_float((unsigned)(Rape >> 32)); int ape_i = (int)(Rape & 0xFFFFFFFFull);

    __syncthreads();   // protect s_red/s_cw before hist reuse

    float mn_v; int mn_i;
    if (k_neg > 0) {
        radix_select_reg(u, negbits, 1u, (k_neg - 1) >> 1, hist, s_wt, s_sel, tid, mn_v, mn_i);
    } else { mn_v = 0.f; mn_i = 0; }
    float mp_v; int mp_i;
    if (k_pos > 0) {
        radix_select_reg(u, negbits, 0u, (k_pos - 1) >> 1, hist, s_wt, s_sel, tid, mp_v, mp_i);
    } else { mp_v = 0.f; mp_i = 0; }

    if (tid == 0) {
        float an_t  = dTrow[an_i];
        float ap_t  = dTrow[ap_i];
        float ane_t = dTrow[ane_i];
        float ape_t = dTrow[ape_i];
        float mn_t  = dTrow[mn_i];
        float mp_t  = dTrow[mp_i];
        terms[i]            = pair_term(an_v,  ap_v,  an_t,  ap_t);   // d-branch
        terms[NROW + i]     = pair_term(ane_v, ape_v, ane_t, ape_t);  // e-branch
        terms[2*NROW + i]   = pair_term(mn_v,  mp_v,  mn_t,  mp_t);   // m-branch
    }
}

// ---------------------------------------------------------------------------
// Kernel 4: deterministic final reduction + decay weights from epoch.
// ---------------------------------------------------------------------------
__global__ __launch_bounds__(256) void k_finalize(const float* __restrict__ terms,
    const void* __restrict__ epoch_p, float* __restrict__ out)
{
    __shared__ float red[256];
    int tid = threadIdx.x;
    float s0 = 0.f, s1 = 0.f, s2 = 0.f;
    for (int j = tid; j < NROW; j += 256) {
        s0 += terms[j];
        s1 += terms[NROW + j];
        s2 += terms[2*NROW + j];
    }
    float tot[3];
    float sv[3] = {s0, s1, s2};
    for (int t = 0; t < 3; ++t) {
        red[tid] = sv[t];
        __syncthreads();
        for (int st = 128; st > 0; st >>= 1) {
            if (tid < st) red[tid] += red[tid + st];
            __syncthreads();
        }
        tot[t] = red[0];
        __syncthreads();
    }
    if (tid == 0) {
        int ei = *(const int*)epoch_p;
        double step;
        if (ei >= 0 && ei < 100000) step = (double)ei;
        else step = (double)(*(const float*)epoch_p);
        const double PI = 3.14159265358979323846;
        double de = 0.5 * 0.75 * (1.0 + cos(PI * step / 120.0));
        double dm = 0.5 * 0.75 * (1.0 + cos(PI * step / 240.0));
        double e = (step < 120.0) ? de : 0.0;
        double m = dm;
        double d = 3.0 - e - m;
        double loss_d = (double)tot[0] / (double)NROW;
        double loss_e = (double)tot[1] / (double)NROW;
        double loss_m = (double)tot[2] / (double)NROW;
        out[0] = (float)(loss_e * e + loss_m * m + loss_d * d);
    }
}

// ---------------------------------------------------------------------------
extern "C" void kernel_launch(void* const* d_in, const int* in_sizes, int n_in,
                              void* d_out, int out_size, void* d_ws, size_t ws_size,
                              hipStream_t stream)
{
    (void)in_sizes; (void)n_in; (void)out_size; (void)ws_size;
    const float* t_in = (const float*)d_in[0];
    const float* s_in = (const float*)d_in[1];
    const void*  epoch = d_in[2];
    float* out = (float*)d_out;

    char* ws = (char*)d_ws;
    size_t off = 0;
    unsigned short* T1 = (unsigned short*)(ws + off); off += (size_t)NROW * DIM * 2;
    unsigned short* T2 = (unsigned short*)(ws + off); off += (size_t)NROW * DIM * 2;
    unsigned short* S1 = (unsigned short*)(ws + off); off += (size_t)NROW * DIM * 2;
    unsigned short* S2 = (unsigned short*)(ws + off); off += (size_t)NROW * DIM * 2;
    float* t2v   = (float*)(ws + off); off += (size_t)NROW * 4;
    float* s2v   = (float*)(ws + off); off += (size_t)NROW * 4;
    float* distT = (float*)(ws + off); off += (size_t)NROW * NROW * 4;
    float* distS = (float*)(ws + off); off += (size_t)NROW * NROW * 4;
    float* terms = (float*)(ws + off); off += (size_t)3 * NROW * 4;

    k_norm_split<<<NROW, 256, 0, stream>>>(t_in, T1, T2, t2v);
    k_norm_split<<<NROW, 256, 0, stream>>>(s_in, S1, S2, s2v);
    k_gemm_mfma<<<dim3(32, 32), 256, 0, stream>>>(T1, T2, S1, S2, t2v, s2v, distT, distS);
    k_rowstats<<<NROW, 256, 0, stream>>>(distS, distT, terms);
    k_finalize<<<1, 256, 0, stream>>>(terms, epoch, out);
}